// Round 1
// baseline (570.858 us; speedup 1.0000x reference)
//
#include <hip/hip_runtime.h>
#include <cstdint>
#include <cstddef>

// Problem constants
#define B_    64
#define H_    8
#define N_    16384
#define M_    64
#define C_    1024
#define IVH_  198          // 3*M+6
#define J_    1584         // H*IVH
#define NCHUNK_ 64         // N/256

__device__ __forceinline__ float softplus_f(float x) {
    return (x > 20.f) ? x : log1pf(__expf(x));
}
__device__ __forceinline__ float sigmoid_f(float x) {
    return 1.f / (1.f + __expf(-x));
}

// DPP lane move within 16-lane row. CTRL: 0xB1=quad xor1, 0x4E=quad xor2,
// 0x128=row_ror:8, 0x124=row_ror:4.
template<int CTRL>
__device__ __forceinline__ float dppf(float x) {
    return __int_as_float(__builtin_amdgcn_update_dpp(
        0, __float_as_int(x), CTRL, 0xF, 0xF, true));
}
// full 16-lane sum; every lane of the row ends with the total, zero DS ops.
#define RED16(v) { v += dppf<0xB1>(v); v += dppf<0x4E>(v); \
                   v += dppf<0x128>(v); v += dppf<0x124>(v); }

__device__ __forceinline__ float sel8(const float p[8], int i) {
    float r01 = (i & 1) ? p[1] : p[0];
    float r23 = (i & 1) ? p[3] : p[2];
    float r45 = (i & 1) ? p[5] : p[4];
    float r67 = (i & 1) ? p[7] : p[6];
    float a = (i & 2) ? r23 : r01;
    float c = (i & 2) ? r67 : r45;
    return (i & 4) ? c : a;
}

// ---------------------------------------------------------------------------
// Kernel 1: iv = x @ W (no bias; consumers add it). grid (25, 4, 16), block 64.
// 16 c-chunks of 64 -> 1600 blocks; unroll 8 keeps 8 W loads in flight.
__global__ __launch_bounds__(64) void k_gemm(const float* __restrict__ x,
                                             const float* __restrict__ W,
                                             float* __restrict__ iv) {
    int lane = threadIdx.x;
    int j = blockIdx.x * 64 + lane;
    bool valid = (j < J_);
    int b0 = blockIdx.y * 16;
    int c0 = blockIdx.z * 64;
    const float* xb = x + (size_t)b0 * C_;
    float acc[16];
    #pragma unroll
    for (int i = 0; i < 16; ++i) acc[i] = 0.f;
    #pragma unroll 8
    for (int c = c0; c < c0 + 64; ++c) {
        float wv = valid ? W[(size_t)c * J_ + j] : 0.f;
        #pragma unroll
        for (int bi = 0; bi < 16; ++bi)
            acc[bi] = fmaf(xb[(size_t)bi * C_ + c], wv, acc[bi]);
    }
    if (valid) {
        #pragma unroll
        for (int bi = 0; bi < 16; ++bi)
            atomicAdd(&iv[(size_t)(b0 + bi) * J_ + j], acc[bi]);
    }
}

// ---------------------------------------------------------------------------
// Kernel 2 (pass A): derives k, beta, ||k|| from iv directly (k_params gone);
// beta/||k|| folded into k fragments; 16-lane reduce is pure-DPP (no DS).
// grid (NCHUNK, B), block 256.
__global__ __launch_bounds__(256, 4) void k_passA(
        const float* __restrict__ mem, const float* __restrict__ iv,
        const float* __restrict__ bias, float* __restrict__ z,
        float* __restrict__ pmax, float* __restrict__ psum) {
    __shared__ float zl[8 * 257];      // [h*257 + row]
    int t = threadIdx.x;
    int b = blockIdx.y;
    int n0 = blockIdx.x << 8;
    int w = t >> 6, lane = t & 63, sub = lane >> 4, mq = lane & 15;

    // k fragments (this lane's 4 m's per h) + norms via DPP row-reduce
    const float* ivb = iv + (size_t)b * J_;
    float4 kreg[8];
    float nq[8];
    #pragma unroll
    for (int h = 0; h < 8; ++h) {
        const float* ivh = ivb + h * IVH_;
        const float* bbh = bias + h * IVH_;
        float2 a0 = *(const float2*)(ivh + mq * 4);
        float2 a1 = *(const float2*)(ivh + mq * 4 + 2);
        float2 c0 = *(const float2*)(bbh + mq * 4);
        float2 c1 = *(const float2*)(bbh + mq * 4 + 2);
        float4 kv = make_float4(a0.x + c0.x, a0.y + c0.y, a1.x + c1.x, a1.y + c1.y);
        float q = kv.x * kv.x + kv.y * kv.y + kv.z * kv.z + kv.w * kv.w;
        RED16(q);                      // all 16 lanes get full ||k||^2
        nq[h] = q;
        kreg[h] = kv;
    }
    float kn[8];
    #pragma unroll
    for (int h = 0; h < 8; ++h) {
        kn[h] = sqrtf(nq[h]);
        float v0 = ivb[h * IVH_ + 64] + bias[h * IVH_ + 64];
        float s = softplus_f(v0) / kn[h];      // beta / ||k||
        kreg[h].x *= s; kreg[h].y *= s; kreg[h].z *= s; kreg[h].w *= s;
    }
    // beta*dot/(kn*rn+1e-16) == (beta/kn)*dot/(rn + 1e-16/kn)
    float epsl = 1e-16f / sel8(kn, mq & 7);

    const float* mb = mem + ((size_t)b * N_ + n0) * M_;
    #pragma unroll
    for (int rr = 0; rr < 16; ++rr) {
        int row = (w << 6) + (rr << 2) + sub;
        float4 mv = *(const float4*)(mb + (size_t)row * M_ + mq * 4);
        float pr[9];
        #pragma unroll
        for (int h = 0; h < 8; ++h)
            pr[h] = kreg[h].x * mv.x + kreg[h].y * mv.y
                  + kreg[h].z * mv.z + kreg[h].w * mv.w;
        pr[8] = mv.x * mv.x + mv.y * mv.y + mv.z * mv.z + mv.w * mv.w;
        #pragma unroll
        for (int i = 0; i < 9; ++i) { float vv = pr[i]; RED16(vv); pr[i] = vv; }
        if (mq < 8) {
            float rn = sqrtf(pr[8]);
            zl[mq * 257 + row] = sel8(pr, mq) / (rn + epsl);
        }
    }
    __syncthreads();

    // global z store (coalesced per h)
    #pragma unroll
    for (int h = 0; h < 8; ++h)
        z[(((size_t)b * 8 + h) << 14) + n0 + t] = zl[h * 257 + t];

    // chunk softmax partials: wave w handles h = 2w, 2w+1
    #pragma unroll
    for (int q = 0; q < 2; ++q) {
        int h = w * 2 + q;
        float a0 = zl[h * 257 + lane],       a1 = zl[h * 257 + lane + 64];
        float a2 = zl[h * 257 + lane + 128], a3 = zl[h * 257 + lane + 192];
        float mx = fmaxf(fmaxf(a0, a1), fmaxf(a2, a3));
        #pragma unroll
        for (int o = 32; o > 0; o >>= 1) mx = fmaxf(mx, __shfl_down(mx, o, 64));
        mx = __shfl(mx, 0, 64);
        float se = __expf(a0 - mx) + __expf(a1 - mx) + __expf(a2 - mx) + __expf(a3 - mx);
        #pragma unroll
        for (int o = 32; o > 0; o >>= 1) se += __shfl_down(se, o, 64);
        if (lane == 0) {
            pmax[(((size_t)b * 8 + h) << 6) + blockIdx.x] = mx;
            psum[(((size_t)b * 8 + h) << 6) + blockIdx.x] = se;
        }
    }
}

// ---------------------------------------------------------------------------
// Kernel 3 (pass B): prologue computes softmax stats (was k_stats) + g/s/gamma
// (was k_params) per block; traversal reversed (boustrophedon) so the mem
// re-read starts on the LLC-resident tail of passA's stream.
__global__ __launch_bounds__(256, 4) void k_passB(
        const float* __restrict__ mem, const float* __restrict__ z,
        const float* __restrict__ wprev, const float* __restrict__ iv,
        const float* __restrict__ bias, const float* __restrict__ pmax,
        const float* __restrict__ psum, float* __restrict__ out_w,
        float* __restrict__ sumwp, float* __restrict__ readAcc) {
    __shared__ float smem[3072 + 2064 + 32];
    __shared__ float pl[64];           // [h*8 + {0:Mx,1:iS,2:g,3:s0,4:s1,5:s2,6:gam}]
    float* wp_s  = smem;               // [row*12 + 0..7]
    float* wgl   = smem + 3072;        // [h*258 + idx] (phase 1)
    float* racc2 = smem + 3072;        // [2048] (phase 2, overlaps wgl)
    float* sums  = smem + 3072 + 2064; // [w*8+h]

    int t = threadIdx.x;
    int b  = (B_ - 1) - blockIdx.y;        // reversed
    int ck = (NCHUNK_ - 1) - blockIdx.x;   // reversed
    int n0 = ck << 8;
    int n = n0 + t;
    int w = t >> 6, lane = t & 63, sub = lane >> 4, mq = lane & 15;

    // prologue: per-(b,h) softmax stats from chunk partials; wave w -> h=2w,2w+1
    #pragma unroll
    for (int q = 0; q < 2; ++q) {
        int h = w * 2 + q;
        size_t bh = (size_t)b * 8 + h;
        float m = pmax[(bh << 6) + lane];
        float s = psum[(bh << 6) + lane];
        float mx = m;
        #pragma unroll
        for (int o = 32; o > 0; o >>= 1) mx = fmaxf(mx, __shfl_xor(mx, o, 64));
        float sc = s * __expf(m - mx);
        #pragma unroll
        for (int o = 32; o > 0; o >>= 1) sc += __shfl_xor(sc, o, 64);
        if (lane == 0) { pl[h * 8 + 0] = mx; pl[h * 8 + 1] = 1.f / sc; }
    }
    if (t < 8) {                      // g, s0..2, gamma from iv directly
        const float* ivh = iv + (size_t)b * J_ + t * IVH_;
        const float* bbh = bias + t * IVH_;
        float v1 = ivh[65] + bbh[65];
        float v2 = ivh[66] + bbh[66];
        float v3 = ivh[67] + bbh[67];
        float v4 = ivh[68] + bbh[68];
        float v5 = ivh[69] + bbh[69];
        float mx3 = fmaxf(v2, fmaxf(v3, v4));
        float e2 = __expf(v2 - mx3), e3 = __expf(v3 - mx3), e4 = __expf(v4 - mx3);
        float inv = 1.f / (e2 + e3 + e4);
        pl[t * 8 + 2] = sigmoid_f(v1);
        pl[t * 8 + 3] = e2 * inv;
        pl[t * 8 + 4] = e3 * inv;
        pl[t * 8 + 5] = e4 * inv;
        pl[t * 8 + 6] = 1.f + softplus_f(v5);
    }
    __syncthreads();

    // phase 1: wg into LDS (with circular halo)
    #pragma unroll
    for (int h = 0; h < 8; ++h) {
        size_t bh = (size_t)b * 8 + h;
        float Mx = pl[h * 8 + 0], iS = pl[h * 8 + 1];
        float g = pl[h * 8 + 2];
        float wc = __expf(z[(bh << 14) + n] - Mx) * iS;
        wgl[h * 258 + t + 1] = fmaf(g, wc, (1.f - g) * wprev[(bh << 14) + n]);
    }
    if (t < 2) {
        int nh   = (t == 0) ? ((n0 + N_ - 1) & (N_ - 1)) : ((n0 + 256) & (N_ - 1));
        int slot = (t == 0) ? 0 : 257;
        #pragma unroll
        for (int h = 0; h < 8; ++h) {
            size_t bh = (size_t)b * 8 + h;
            float Mx = pl[h * 8 + 0], iS = pl[h * 8 + 1];
            float g = pl[h * 8 + 2];
            float wc = __expf(z[(bh << 14) + nh] - Mx) * iS;
            wgl[h * 258 + slot] = fmaf(g, wc, (1.f - g) * wprev[(bh << 14) + nh]);
        }
    }
    __syncthreads();

    // phase 1b: shift + sharpen -> wp
    float wpv[8];
    #pragma unroll
    for (int h = 0; h < 8; ++h) {
        size_t bh = (size_t)b * 8 + h;
        float s0 = pl[h * 8 + 3], s1 = pl[h * 8 + 4], s2 = pl[h * 8 + 5];
        float gam = pl[h * 8 + 6];
        float wsv = s0 * wgl[h * 258 + t] + s1 * wgl[h * 258 + t + 1]
                  + s2 * wgl[h * 258 + t + 2];
        float v = __powf(wsv, gam);
        wpv[h] = v;
        out_w[(bh << 14) + n] = v;      // unnormalized; k_finish rescales
    }
    // sumwp: register butterfly per wave
    #pragma unroll
    for (int h = 0; h < 8; ++h) {
        float s = wpv[h];
        #pragma unroll
        for (int o = 32; o > 0; o >>= 1) s += __shfl_down(s, o, 64);
        if (lane == 0) sums[w * 8 + h] = s;
    }
    // stage wp (stride 12: 16B-aligned, <=2-way bank alias)
    *(float4*)(wp_s + t * 12)     = make_float4(wpv[0], wpv[1], wpv[2], wpv[3]);
    *(float4*)(wp_s + t * 12 + 4) = make_float4(wpv[4], wpv[5], wpv[6], wpv[7]);
    __syncthreads();
    if (t < 8)
        atomicAdd(&sumwp[b * 8 + t], sums[t] + sums[8 + t] + sums[16 + t] + sums[24 + t]);

    // phase 2: coalesced weighted read, 16 lanes per row
    float4 acc[8];
    #pragma unroll
    for (int h = 0; h < 8; ++h) acc[h] = make_float4(0.f, 0.f, 0.f, 0.f);
    const float* mb = mem + ((size_t)b * N_ + n0) * M_;
    #pragma unroll
    for (int rr = 0; rr < 16; ++rr) {
        int row = (w << 6) + (rr << 2) + sub;
        float4 mv = *(const float4*)(mb + (size_t)row * M_ + mq * 4);
        float4 wA = *(const float4*)(wp_s + row * 12);
        float4 wB = *(const float4*)(wp_s + row * 12 + 4);
        float wv8[8] = {wA.x, wA.y, wA.z, wA.w, wB.x, wB.y, wB.z, wB.w};
        #pragma unroll
        for (int h = 0; h < 8; ++h) {
            acc[h].x = fmaf(wv8[h], mv.x, acc[h].x);
            acc[h].y = fmaf(wv8[h], mv.y, acc[h].y);
            acc[h].z = fmaf(wv8[h], mv.z, acc[h].z);
            acc[h].w = fmaf(wv8[h], mv.w, acc[h].w);
        }
    }
    #pragma unroll
    for (int h = 0; h < 8; ++h) {
        #pragma unroll
        for (int o = 32; o >= 16; o >>= 1) {
            acc[h].x += __shfl_down(acc[h].x, o, 64);
            acc[h].y += __shfl_down(acc[h].y, o, 64);
            acc[h].z += __shfl_down(acc[h].z, o, 64);
            acc[h].w += __shfl_down(acc[h].w, o, 64);
        }
    }
    if (lane < 16) {
        #pragma unroll
        for (int h = 0; h < 8; ++h)
            *(float4*)(racc2 + ((w * 8 + h) << 6) + mq * 4) = acc[h];
    }
    __syncthreads();
    #pragma unroll
    for (int r = 0; r < 2; ++r) {
        int idx = r * 256 + t;
        float s = racc2[idx] + racc2[512 + idx] + racc2[1024 + idx] + racc2[1536 + idx];
        atomicAdd(&readAcc[(size_t)b * 512 + idx], s);
    }
}

// ---------------------------------------------------------------------------
// Kernel 4: fused epilogue. All blocks normalize w (float4/thread); blocks
// 0..127 also produce read_data, 128..255 out_e, 256..383 out_a.
__global__ void k_finish(float* __restrict__ out_w, const float* __restrict__ sumwp,
                         const float* __restrict__ readAcc, const float* __restrict__ iv,
                         const float* __restrict__ bias, float* __restrict__ out_rd,
                         float* __restrict__ out_e, float* __restrict__ out_a) {
    int t = threadIdx.x;
    size_t idx = (size_t)blockIdx.x * 256 + t;   // float4 index
    int bh = (int)(idx >> 12);
    float inv = 1.f / (sumwp[bh] + 1e-16f);
    float4* p = (float4*)out_w + idx;
    float4 v = *p;
    v.x *= inv; v.y *= inv; v.z *= inv; v.w *= inv;
    *p = v;
    if (blockIdx.x < 128) {
        int i = blockIdx.x * 256 + t;            // 32768 total
        out_rd[i] = readAcc[i] / (sumwp[i >> 6] + 1e-16f);
    } else if (blockIdx.x < 256) {
        int i = (blockIdx.x - 128) * 256 + t;
        int bb = i >> 9, h = (i >> 6) & 7, m = i & 63;
        int off = h * IVH_ + 70 + m;             // M+6 = 70
        out_e[i] = sigmoid_f(iv[(size_t)bb * J_ + off] + bias[off]);
    } else if (blockIdx.x < 384) {
        int i = (blockIdx.x - 256) * 256 + t;
        int bb = i >> 9, h = (i >> 6) & 7, m = i & 63;
        int off = h * IVH_ + 134 + m;            // 2M+6 = 134
        out_a[i] = iv[(size_t)bb * J_ + off] + bias[off];
    }
}

// ---------------------------------------------------------------------------
extern "C" void kernel_launch(void* const* d_in, const int* in_sizes, int n_in,
                              void* d_out, int out_size, void* d_ws, size_t ws_size,
                              hipStream_t stream) {
    const float* x     = (const float*)d_in[0];
    const float* mem   = (const float*)d_in[1];
    const float* wprev = (const float*)d_in[2];
    const float* W     = (const float*)d_in[3];
    const float* bias  = (const float*)d_in[4];

    float* out   = (float*)d_out;
    float* out_rd = out;                         // 32768
    float* out_w  = out + 32768;                 // 8388608
    float* out_e  = out + 32768 + 8388608;       // 32768
    float* out_a  = out_e + 32768;               // 32768

    float* ws      = (float*)d_ws;
    float* iv      = ws;                  // 101376  (zeroed)
    float* sumwp   = iv + 101376;         // 512     (zeroed)
    float* readAcc = sumwp + 512;         // 32768   (zeroed)
    float* zbuf    = readAcc + 32768;     // 8388608
    float* pmax    = zbuf + 8388608;      // 32768
    float* psum    = pmax + 32768;        // 32768

    hipMemsetAsync(iv, 0, (size_t)(101376 + 512 + 32768) * 4, stream);

    k_gemm  <<<dim3(25, 4, 16), 64, 0, stream>>>(x, W, iv);
    k_passA <<<dim3(NCHUNK_, B_), 256, 0, stream>>>(mem, iv, bias, zbuf, pmax, psum);
    k_passB <<<dim3(NCHUNK_, B_), 256, 0, stream>>>(mem, zbuf, wprev, iv, bias,
                                                    pmax, psum, out_w, sumwp, readAcc);
    k_finish<<<8192, 256, 0, stream>>>(out_w, sumwp, readAcc, iv, bias,
                                       out_rd, out_e, out_a);
}